// Round 7
// baseline (6303.307 us; speedup 1.0000x reference)
//
#include <hip/hip_runtime.h>

typedef unsigned short u16;
typedef unsigned int u32;
typedef __bf16 bf16x8 __attribute__((ext_vector_type(8)));
typedef float f32x4 __attribute__((ext_vector_type(4)));

#define B_ 256
#define T_ 128
#define E_ 300
#define EP 320
#define H_ 2048
#define G_ 8192

// ws layout (bytes) -- R1-verified
#define OFF_XBF   0UL           // [T][B][EP] bf16           = 20,971,520
#define OFF_WPK   20971520UL    // 256 blk x 131072 B packed W_hh frags = 33,554,432
#define OFF_WIP   54525952UL    // 256 blk x 20480 B packed W_ih frags  =  5,242,880
#define OFF_BIAS  59768832UL    // 8192 f32
#define OFF_HBUF  59801600UL    // 2 x [256][2048] bf16
#define OFF_BAR   61898752UL    // 128 u32 step counters

// plain global->LDS, 16B per lane, lane-linear dest
#define GLDS16(gp, sp)                                                    \
  __builtin_amdgcn_global_load_lds(                                       \
      (__attribute__((address_space(1))) void*)(void*)(gp),               \
      (__attribute__((address_space(3))) void*)(sp), 16, 0, 0)

__device__ __forceinline__ u16 f2bf(float f) {
  u32 u = __builtin_bit_cast(u32, f);
  return (u16)((u + 0x7FFFu + ((u >> 16) & 1u)) >> 16);
}
__device__ __forceinline__ float sigm_f(float x) {
  return __builtin_amdgcn_rcpf(1.0f + __expf(-x));
}
__device__ __forceinline__ float tanh_f(float x) {
  return 1.0f - 2.0f * __builtin_amdgcn_rcpf(1.0f + __expf(2.0f * x));
}

// ---------------- prep: R1-verified frag packing ----------------
// W_hh packed per block bid (8 h-cols j0=bid*8): [kt 0..63][f 0..1][lane][8]
//   lane ln -> col n=ln&15: gate = f*2 + (n>>3), c = n&7 ; k = kt*32 + (ln>>4)*8 + e
// W_ih packed identically with kt 0..9 over EP=320 (zero-pad past E=300).
__global__ void prep_kernel(const float* __restrict__ x, const float* __restrict__ Wih,
                            const float* __restrict__ Whh, const float* __restrict__ bih,
                            const float* __restrict__ bhh, u16* __restrict__ xbf,
                            u16* __restrict__ wpk, u16* __restrict__ wip,
                            float* __restrict__ biasc, u32* __restrict__ bar) {
  const long NX = (long)T_ * B_ * EP;
  const long NWPK = 256L * 65536L;
  const long NWIP = 256L * 10240L;
  const long NBS = G_;
  const long NBAR = T_;
  const long total = NX + NWPK + NWIP + NBS + NBAR;
  for (long q = (long)blockIdx.x * blockDim.x + threadIdx.x; q < total;
       q += (long)gridDim.x * blockDim.x) {
    long r = q;
    if (r < NX) {
      int t = (int)(r / (B_ * EP));
      int rem = (int)(r % (B_ * EP));
      int b = rem / EP, e = rem % EP;
      float v = (e < E_) ? x[((long)b * T_ + t) * E_ + e] : 0.0f;
      xbf[r] = f2bf(v);
    } else if ((r -= NX) < NWPK) {
      int blk = (int)(r >> 16);
      int qq = (int)(r & 65535);
      int e = qq & 7, ln = (qq >> 3) & 63, f = (qq >> 9) & 1, k2 = qq >> 10;
      int gate = f * 2 + ((ln >> 3) & 1);
      int grow = gate * H_ + blk * 8 + (ln & 7);
      int k = k2 * 32 + ((ln >> 4) & 3) * 8 + e;
      wpk[r] = f2bf(Whh[(long)grow * H_ + k]);
    } else if ((r -= NWPK) < NWIP) {
      int blk = (int)(r / 10240);
      int qq = (int)(r % 10240);
      int e = qq & 7, ln = (qq >> 3) & 63, f = (qq >> 9) & 1, k2 = qq >> 10;
      int gate = f * 2 + ((ln >> 3) & 1);
      int grow = gate * H_ + blk * 8 + (ln & 7);
      int k = k2 * 32 + ((ln >> 4) & 3) * 8 + e;
      wip[r] = f2bf((k < E_) ? Wih[(long)grow * E_ + k] : 0.0f);
    } else if ((r -= NWIP) < NBS) {
      biasc[r] = bih[r] + bhh[r];
    } else {
      r -= NBS;
      bar[r] = 0;
    }
  }
}

// ---------------- main persistent LSTM kernel ----------------
// 256 blocks x 512 thr (8 waves), 1 block/CU. Block bid owns 8 h-cols
// (j0=bid*8): its 32 gate-rows x K=2048 of W_hh = 128 KiB RESIDENT IN LDS
// for all 128 steps (zero steady-state W traffic -- removes the 20 MB/step
// L2-thrash miss stream that paced R0/R2/R4). W_ih slice in 80 VGPRs.
// A operand (x_t, then h_t): all 256 batch rows; wave w owns rows
// [32w,32w+32), staged into a PER-WAVE 4 KB LDS double-buffer in MFMA
// fragment-linear order (GLDS dest = uniform base + lane*16B). Each wave
// stages and reads ONLY its own slice -> completion tracked by its own
// counted vmcnt -> ZERO barriers inside the K-loops; waves free-run.
// h coherence (R1-verified protocol): producers store h sc0sc1; consumers
// flag-spin -> __syncthreads -> agent-acquire fence (inv L1/L2) -> plain
// cached loads (h L2-dedups across the XCD's 32 CUs).
__global__ void __launch_bounds__(512, 2)
lstm_kernel(const u16* __restrict__ xbf, const u16* __restrict__ wpk,
            const u16* __restrict__ wip, const float* __restrict__ biasc,
            u16* __restrict__ hbuf, u32* __restrict__ bar, float* __restrict__ out) {
  __shared__ __align__(16) u16 Wl[65536];          // 128 KB resident W_hh frags
  __shared__ __align__(16) u16 Ah[8][2][2][512];   // 32 KB per-wave A dbuf

  const int tid = threadIdx.x;
  const int l = tid & 63;
  const int w = tid >> 6;            // 8 waves
  const int bid = blockIdx.x;
  const int rowbase = w << 5;        // wave's 32 batch rows
  const int rl = l & 15;             // fragment row lane
  const int kb = (l >> 4) << 3;      // k-offset within 32-k tile
  const int jc = (bid << 3) + (l & 7);
  const int half = (l >> 3) & 1;     // 0: lane holds {i,g}; 1: {f,o}

  // ---- one-time: W_hh -> LDS (frag-linear == lane-linear GLDS) ----
  {
    const u16* wsrc = wpk + ((size_t)bid << 16);
    u16* wdst = &Wl[w << 9];
#pragma unroll
    for (int i = 0; i < 16; ++i)
      GLDS16(wsrc + (i << 12) + (tid << 3), wdst + (i << 12));
  }
  // ---- one-time: W_ih -> registers (20 frags x 16 B = 80 VGPR) ----
  bf16x8 wih[2][10];
  {
    const u16* wisrc = wip + (size_t)bid * 10240 + (l << 3);
#pragma unroll
    for (int kt = 0; kt < 10; ++kt)
#pragma unroll
      for (int f = 0; f < 2; ++f)
        wih[f][kt] = *(const bf16x8*)(wisrc + (kt << 10) + (f << 9));
  }
  const float bi = biasc[jc];
  const float bff = biasc[H_ + jc];
  const float bg = biasc[2 * H_ + jc];
  const float bo = biasc[3 * H_ + jc];
  asm volatile("s_waitcnt vmcnt(0)" ::: "memory");
  __syncthreads();

  float cst[2][4];
#pragma unroll
  for (int rf = 0; rf < 2; ++rf)
#pragma unroll
    for (int r = 0; r < 4; ++r) cst[rf][r] = 0.0f;

  u16* Amy = &Ah[w][0][0][0];        // 2048 u16 = 4 KB per wave

#pragma unroll 1
  for (int t = 0; t < T_; ++t) {
    const u16* hcur = hbuf + (size_t)(t & 1) * (B_ * H_);
    u16* hnxt = hbuf + (size_t)((t + 1) & 1) * (B_ * H_);
    const u16* xsrc = xbf + (size_t)t * (B_ * EP);

    f32x4 acc[2][2];                 // [rowtile][ntile-f]
#pragma unroll
    for (int i = 0; i < 2; ++i) {
      acc[i][0] = (f32x4){0.f, 0.f, 0.f, 0.f};
      acc[i][1] = (f32x4){0.f, 0.f, 0.f, 0.f};
    }

    // ---- x phase: 10 self-paced ktiles, per-wave dbuf, NO barriers ----
    auto stageX = [&](int kt, int b) {
#pragma unroll
      for (int i = 0; i < 2; ++i) {
        const u16* g = xsrc + (size_t)(rowbase + (i << 4) + rl) * EP + (kt << 5) + kb;
        GLDS16(g, Amy + (b << 10) + (i << 9));
      }
    };
    stageX(0, 0);
#pragma unroll
    for (int kt = 0; kt < 10; ++kt) {
      if (kt < 9) {
        stageX(kt + 1, (kt + 1) & 1);
        asm volatile("s_waitcnt vmcnt(2)" ::: "memory");  // own chunk kt staged
      } else {
        asm volatile("s_waitcnt vmcnt(0)" ::: "memory");
      }
      __builtin_amdgcn_sched_barrier(0);
      const u16* ap = Amy + ((kt & 1) << 10) + (l << 3);
      bf16x8 a0 = *(const bf16x8*)ap;
      bf16x8 a1 = *(const bf16x8*)(ap + 512);
      acc[0][0] = __builtin_amdgcn_mfma_f32_16x16x32_bf16(a0, wih[0][kt], acc[0][0], 0, 0, 0);
      acc[0][1] = __builtin_amdgcn_mfma_f32_16x16x32_bf16(a0, wih[1][kt], acc[0][1], 0, 0, 0);
      acc[1][0] = __builtin_amdgcn_mfma_f32_16x16x32_bf16(a1, wih[0][kt], acc[1][0], 0, 0, 0);
      acc[1][1] = __builtin_amdgcn_mfma_f32_16x16x32_bf16(a1, wih[1][kt], acc[1][1], 0, 0, 0);
    }

    // ---- h phase (skipped at t=0: h==0): 64 self-paced ktiles ----
    if (t > 0) {
      if (tid == 0) {
        while (__hip_atomic_load(&bar[t - 1], __ATOMIC_RELAXED,
                                 __HIP_MEMORY_SCOPE_AGENT) < 256u)
          __builtin_amdgcn_s_sleep(2);
      }
      __syncthreads();
      // drop stale h lines from L1/L2; cheap: nothing persistent in L2 (W in LDS)
      __builtin_amdgcn_fence(__ATOMIC_ACQUIRE, "agent");

      auto stageH = [&](int kt, int b) {
#pragma unroll
        for (int i = 0; i < 2; ++i) {
          const u16* g = hcur + (size_t)(rowbase + (i << 4) + rl) * H_ + (kt << 5) + kb;
          GLDS16(g, Amy + (b << 10) + (i << 9));
        }
      };
      stageH(0, 0);
#pragma unroll 2
      for (int kt = 0; kt < 64; ++kt) {
        if (kt < 63) {
          stageH(kt + 1, (kt + 1) & 1);
          asm volatile("s_waitcnt vmcnt(2)" ::: "memory");
        } else {
          asm volatile("s_waitcnt vmcnt(0)" ::: "memory");
        }
        __builtin_amdgcn_sched_barrier(0);
        const u16* ap = Amy + ((kt & 1) << 10) + (l << 3);
        bf16x8 a0 = *(const bf16x8*)ap;
        bf16x8 a1 = *(const bf16x8*)(ap + 512);
        const u16* bp = &Wl[(kt << 10) + (l << 3)];
        bf16x8 b0 = *(const bf16x8*)bp;
        bf16x8 b1 = *(const bf16x8*)(bp + 512);
        acc[0][0] = __builtin_amdgcn_mfma_f32_16x16x32_bf16(a0, b0, acc[0][0], 0, 0, 0);
        acc[0][1] = __builtin_amdgcn_mfma_f32_16x16x32_bf16(a0, b1, acc[0][1], 0, 0, 0);
        acc[1][0] = __builtin_amdgcn_mfma_f32_16x16x32_bf16(a1, b0, acc[1][0], 0, 0, 0);
        acc[1][1] = __builtin_amdgcn_mfma_f32_16x16x32_bf16(a1, b1, acc[1][1], 0, 0, 0);
      }
    }

    // ---- pointwise (R1-verified): frag0={i|f}(c), frag1={g|o}(c); partner
    // lane l^8 holds the complementary gates; both halves compute h redundantly.
#pragma unroll
    for (int rf = 0; rf < 2; ++rf) {
#pragma unroll
      for (int r = 0; r < 4; ++r) {
        float v0 = acc[rf][0][r];
        float v1 = acc[rf][1][r];
        float p0 = __shfl_xor(v0, 8);
        float p1 = __shfl_xor(v1, 8);
        float iv = half ? p0 : v0;
        float fv = half ? v0 : p0;
        float gv = half ? p1 : v1;
        float ov = half ? v1 : p1;
        float ig = sigm_f(iv + bi);
        float fg = sigm_f(fv + bff);
        float gg = tanh_f(gv + bg);
        float og = sigm_f(ov + bo);
        float cc = fg * cst[rf][r] + ig * gg;
        cst[rf][r] = cc;
        float h = og * tanh_f(cc);
        int row = rowbase + (rf << 4) + ((l >> 4) << 2) + r;
        if (t < T_ - 1) {
          if ((l & 8) == 0) {
            u16 hv = f2bf(h);
            u16* hp = hnxt + (size_t)row * H_ + jc;
            asm volatile("global_store_short %0, %1, off sc0 sc1"
                         :: "v"(hp), "v"((u32)hv) : "memory");
          }
        } else {
          if ((l & 8) == 0) out[(size_t)row * H_ + jc] = h;
        }
      }
    }

    if (t < T_ - 1) {
      __builtin_amdgcn_s_waitcnt(0);      // h stores reached coherent point
      __syncthreads();                    // all 8 waves drained
      if (tid == 0)
        __hip_atomic_fetch_add(&bar[t], 1u, __ATOMIC_RELAXED,
                               __HIP_MEMORY_SCOPE_AGENT);
    }
  }
}

extern "C" void kernel_launch(void* const* d_in, const int* in_sizes, int n_in,
                              void* d_out, int out_size, void* d_ws, size_t ws_size,
                              hipStream_t stream) {
  const float* x = (const float*)d_in[0];
  const float* Wih = (const float*)d_in[1];
  const float* Whh = (const float*)d_in[2];
  const float* bih = (const float*)d_in[3];
  const float* bhh = (const float*)d_in[4];
  char* ws = (char*)d_ws;
  u16* xbf = (u16*)(ws + OFF_XBF);
  u16* wpk = (u16*)(ws + OFF_WPK);
  u16* wip = (u16*)(ws + OFF_WIP);
  float* biasc = (float*)(ws + OFF_BIAS);
  u16* hbuf = (u16*)(ws + OFF_HBUF);
  u32* bar = (u32*)(ws + OFF_BAR);
  float* out = (float*)d_out;

  hipLaunchKernelGGL(prep_kernel, dim3(2048), dim3(256), 0, stream,
                     x, Wih, Whh, bih, bhh, xbf, wpk, wip, biasc, bar);

  void* args[] = {(void*)&xbf, (void*)&wpk, (void*)&wip,
                  (void*)&biasc, (void*)&hbuf, (void*)&bar, (void*)&out};
  hipLaunchCooperativeKernel((void*)lstm_kernel, dim3(256), dim3(512), args, 0, stream);
}